// Round 2
// baseline (590.673 us; speedup 1.0000x reference)
//
#include <hip/hip_runtime.h>

// Per-image standardization, input (64, 512, 512, 3) fp32.
//
// Single fused kernel with PER-IMAGE sync (not a grid-wide cooperative
// barrier — round-1 showed cg::grid.sync() cost ~135 µs of polling storm):
//   phase 1: per-block {sum, sumsq} partials (coalesced float4 reads)
//   per-image release/acquire counter (32 blocks/image, 64 cachelines)
//   phase 2: per-image mean/inv-std, normalize chunk (L3-served re-read,
//            proven by round-1 FETCH_SIZE == 201 MB), non-temporal stores.
//
// Geometry: 64 images x 32 blocks/image = 2048 blocks x 256 threads.
// __launch_bounds__(256, 8) caps VGPR at 64 -> 8 blocks/CU -> the whole
// 2048-block grid is co-resident (256 CU x 8), so the per-image spin is
// deadlock-free regardless of dispatch order. Additionally, image block
// groups are contiguous, so even a partial in-order dispatch prefix always
// contains complete images that finish and retire (liveness fallback).

#define N_IMG 64
#define ELEMS_PER_IMG 786432
#define VEC4_PER_IMG 196608
#define BLOCKS_PER_IMG 32
#define GRID (N_IMG * BLOCKS_PER_IMG)                    // 2048
#define THREADS 256
#define VEC4_PER_BLOCK (VEC4_PER_IMG / BLOCKS_PER_IMG)   // 6144
#define VEC4_PER_THREAD (VEC4_PER_BLOCK / THREADS)       // 24

// ws layout: [0, 8 KiB): per-image counters, 128 B stride (no false
//            sharing across XCDs); [8 KiB, 24 KiB): 2048 float2 partials.
#define CTR_STRIDE_INTS 32                               // 128 B / image

typedef float v4f __attribute__((ext_vector_type(4)));

__global__ __launch_bounds__(THREADS, 8) void std_fused_spin(
    const v4f* __restrict__ in, v4f* __restrict__ out,
    int* __restrict__ counters, float2* __restrict__ partials) {
    const int img = blockIdx.x >> 5;          // / BLOCKS_PER_IMG
    const int blk = blockIdx.x & 31;          // % BLOCKS_PER_IMG
    const size_t base =
        (size_t)img * VEC4_PER_IMG + (size_t)blk * VEC4_PER_BLOCK;
    const v4f* __restrict__ bin = in + base;

    // ---- phase 1: partial {sum, sumsq} for this block's chunk ----
    float s = 0.f, sq = 0.f;
#pragma unroll
    for (int i = 0; i < VEC4_PER_THREAD; ++i) {
        v4f v = bin[threadIdx.x + i * THREADS];
        s += (v.x + v.y) + (v.z + v.w);
        sq = fmaf(v.x, v.x, sq);
        sq = fmaf(v.y, v.y, sq);
        sq = fmaf(v.z, v.z, sq);
        sq = fmaf(v.w, v.w, sq);
    }

#pragma unroll
    for (int off = 32; off > 0; off >>= 1) {
        s += __shfl_down(s, off);
        sq += __shfl_down(sq, off);
    }
    __shared__ float ss[4], ssq[4];
    const int lane = threadIdx.x & 63;
    const int wave = threadIdx.x >> 6;
    if (lane == 0) { ss[wave] = s; ssq[wave] = sq; }
    __syncthreads();

    // ---- publish partial, then per-image release/acquire sync ----
    int* ctr = counters + img * CTR_STRIDE_INTS;
    if (threadIdx.x == 0) {
        float2 p;
        p.x = (ss[0] + ss[1]) + (ss[2] + ss[3]);
        p.y = (ssq[0] + ssq[1]) + (ssq[2] + ssq[3]);
        partials[blockIdx.x] = p;
        __threadfence();  // belt-and-braces agent-scope release of p
        __hip_atomic_fetch_add(ctr, 1, __ATOMIC_RELEASE,
                               __HIP_MEMORY_SCOPE_AGENT);
        // Only ONE thread per block spins, on one of 64 distinct lines.
        while (__hip_atomic_load(ctr, __ATOMIC_ACQUIRE,
                                 __HIP_MEMORY_SCOPE_AGENT) < BLOCKS_PER_IMG) {
            __builtin_amdgcn_s_sleep(4);
        }
    }
    __syncthreads();  // acquire on thread 0 + barrier orders the whole block

    // ---- phase 2: reduce this image's 32 partials, normalize chunk ----
    __shared__ float s_mean, s_inv;
    if (threadIdx.x < 64) {
        float ps = 0.f, psq = 0.f;
        if (threadIdx.x < BLOCKS_PER_IMG) {
            float2 p = partials[img * BLOCKS_PER_IMG + threadIdx.x];
            ps = p.x;
            psq = p.y;
        }
#pragma unroll
        for (int off = 16; off > 0; off >>= 1) {
            ps += __shfl_down(ps, off);
            psq += __shfl_down(psq, off);
        }
        if (threadIdx.x == 0) {
            const float invN = 1.0f / (float)ELEMS_PER_IMG;
            float mean = ps * invN;
            float var = fmaxf(psq * invN - mean * mean, 0.0f);
            float sd = sqrtf(var);
            float min_sd = 1.0f / sqrtf((float)ELEMS_PER_IMG);  // TF clamp
            sd = fmaxf(sd, min_sd);
            s_mean = mean;
            s_inv = 1.0f / sd;
        }
    }
    __syncthreads();
    const float mean = s_mean;
    const float inv = s_inv;

    v4f* __restrict__ bout = out + base;
#pragma unroll
    for (int i = 0; i < VEC4_PER_THREAD; ++i) {
        const int idx = threadIdx.x + i * THREADS;
        v4f v = bin[idx];  // L3-served: phase 1 just streamed this image
        v4f r;
        r.x = (v.x - mean) * inv;
        r.y = (v.y - mean) * inv;
        r.z = (v.z - mean) * inv;
        r.w = (v.w - mean) * inv;
        __builtin_nontemporal_store(r, &bout[idx]);
    }
}

extern "C" void kernel_launch(void* const* d_in, const int* in_sizes, int n_in,
                              void* d_out, int out_size, void* d_ws, size_t ws_size,
                              hipStream_t stream) {
    const v4f* in = (const v4f*)d_in[0];
    v4f* out = (v4f*)d_out;
    int* counters = (int*)d_ws;                       // 8 KiB
    float2* partials = (float2*)((char*)d_ws + 8192); // 16 KiB

    // Zero the per-image counters (stream-ordered, graph-capture safe).
    hipMemsetAsync(counters, 0, 8192, stream);

    std_fused_spin<<<GRID, THREADS, 0, stream>>>(in, out, counters, partials);
}

// Round 3
// 368.238 us; speedup vs baseline: 1.6041x; 1.6041x over previous
//
#include <hip/hip_runtime.h>

// Per-image standardization, input (64, 512, 512, 3) fp32.
//
// Fused single kernel, FLUSH-FREE per-image sync.
//
// History/evidence:
//  r0: two kernels          -> 118 us kernel-time (dur 360)
//  r1: cg::grid.sync fused  -> 233 us (ideal 403 MB traffic, but 1.7 TB/s)
//  r2: acq/rel spin fused   -> 367 us, WRITE_SIZE inflated +25 MB
// Theory: agent-scope acquire/release compile to L2 wb/inv cache ops on the
// 8-XCD part; polled acquire = storm of buffer_inv serializing at TCC.
// Fix: ALL cross-block control data uses RELAXED agent-scope atomics
// (sc1, L2-bypassing, NO cache maintenance). Producer ordering via explicit
// s_waitcnt vmcnt(0) (completion at coherence point == machine visibility);
// consumer ordering via program-order polling + compiler barrier.
// Bulk input loads stay normal cached loads so phase 2 re-reads hit L2/L3.
//
// Geometry: 64 images x 32 blocks/image = 2048 blocks x 256 threads,
// __launch_bounds__(256, 8): whole grid co-resident (256 CU x 8 blocks),
// so the per-image wait cannot deadlock regardless of dispatch order.

#define N_IMG 64
#define ELEMS_PER_IMG 786432
#define VEC4_PER_IMG 196608
#define BLOCKS_PER_IMG 32
#define GRID (N_IMG * BLOCKS_PER_IMG)                    // 2048
#define THREADS 256
#define VEC4_PER_BLOCK (VEC4_PER_IMG / BLOCKS_PER_IMG)   // 6144
#define VEC4_PER_THREAD (VEC4_PER_BLOCK / THREADS)       // 24

// ws layout:
//   [0, 8 KiB):  per-image control lines, 128 B apart (memset to 0):
//                int[0]=arrival ctr, int[1]=stats flag,
//                int[2]=mean bits,   int[3]=inv-stddev bits
//   [8 KiB, 24 KiB): 2048 x {sum, sumsq} partials (guarded by ctr, no clear)
#define CTRL_INTS_PER_IMG 32   // 128 B stride

typedef float v4f __attribute__((ext_vector_type(4)));

__device__ __forceinline__ void waitcnt_vm0() {
    asm volatile("s_waitcnt vmcnt(0)" ::: "memory");
}

__global__ __launch_bounds__(THREADS, 8) void std_fused_nf(
    const v4f* __restrict__ in, v4f* __restrict__ out,
    int* __restrict__ ctrl, float* __restrict__ partials) {
    const int img = blockIdx.x >> 5;          // / BLOCKS_PER_IMG
    const int blk = blockIdx.x & 31;          // % BLOCKS_PER_IMG
    const size_t base =
        (size_t)img * VEC4_PER_IMG + (size_t)blk * VEC4_PER_BLOCK;
    const v4f* __restrict__ bin = in + base;

    // ---- phase 1: partial {sum, sumsq} for this block's chunk ----
    float s = 0.f, sq = 0.f;
#pragma unroll
    for (int i = 0; i < VEC4_PER_THREAD; ++i) {
        v4f v = bin[threadIdx.x + i * THREADS];  // cached: warms L2/L3
        s += (v.x + v.y) + (v.z + v.w);
        sq = fmaf(v.x, v.x, sq);
        sq = fmaf(v.y, v.y, sq);
        sq = fmaf(v.z, v.z, sq);
        sq = fmaf(v.w, v.w, sq);
    }
#pragma unroll
    for (int off = 32; off > 0; off >>= 1) {
        s += __shfl_down(s, off);
        sq += __shfl_down(sq, off);
    }

    __shared__ float ss[4], ssq[4];
    __shared__ int s_last;
    __shared__ float s_mean, s_inv;
    const int lane = threadIdx.x & 63;
    const int wave = threadIdx.x >> 6;
    if (lane == 0) { ss[wave] = s; ssq[wave] = sq; }
    __syncthreads();

    int* line = ctrl + img * CTRL_INTS_PER_IMG;
    float* stats = (float*)(line + 2);

    // ---- publish partial + arrive (all relaxed, zero cache maintenance) ----
    if (threadIdx.x == 0) {
        const float ps = (ss[0] + ss[1]) + (ss[2] + ss[3]);
        const float pq = (ssq[0] + ssq[1]) + (ssq[2] + ssq[3]);
        __hip_atomic_store(&partials[2 * blockIdx.x + 0], ps,
                           __ATOMIC_RELAXED, __HIP_MEMORY_SCOPE_AGENT);
        __hip_atomic_store(&partials[2 * blockIdx.x + 1], pq,
                           __ATOMIC_RELAXED, __HIP_MEMORY_SCOPE_AGENT);
        waitcnt_vm0();  // partial is at the coherence point before we arrive
        const int old = __hip_atomic_fetch_add(line, 1, __ATOMIC_RELAXED,
                                               __HIP_MEMORY_SCOPE_AGENT);
        s_last = (old == BLOCKS_PER_IMG - 1);
    }
    __syncthreads();

    if (s_last) {
        // Last-arriving block: all 32 partials are complete. Wave 0 reduces
        // them in parallel and publishes {mean, inv} once for the image.
        float ps = 0.f, pq = 0.f;
        if (threadIdx.x < BLOCKS_PER_IMG) {
            const int pi = 2 * (img * BLOCKS_PER_IMG + threadIdx.x);
            ps = __hip_atomic_load(&partials[pi + 0], __ATOMIC_RELAXED,
                                   __HIP_MEMORY_SCOPE_AGENT);
            pq = __hip_atomic_load(&partials[pi + 1], __ATOMIC_RELAXED,
                                   __HIP_MEMORY_SCOPE_AGENT);
        }
        if (threadIdx.x < 64) {  // whole wave 0 participates in shuffles
#pragma unroll
            for (int off = 16; off > 0; off >>= 1) {
                ps += __shfl_down(ps, off);
                pq += __shfl_down(pq, off);
            }
            if (threadIdx.x == 0) {
                const float invN = 1.0f / (float)ELEMS_PER_IMG;
                const float mean = ps * invN;
                const float var = fmaxf(pq * invN - mean * mean, 0.0f);
                const float min_sd = 1.0f / sqrtf((float)ELEMS_PER_IMG);
                const float sd = fmaxf(sqrtf(var), min_sd);  // TF clamp
                const float inv = 1.0f / sd;
                s_mean = mean;
                s_inv = inv;
                __hip_atomic_store(&stats[0], mean, __ATOMIC_RELAXED,
                                   __HIP_MEMORY_SCOPE_AGENT);
                __hip_atomic_store(&stats[1], inv, __ATOMIC_RELAXED,
                                   __HIP_MEMORY_SCOPE_AGENT);
                waitcnt_vm0();  // stats visible before the flag
                __hip_atomic_store(line + 1, 1, __ATOMIC_RELAXED,
                                   __HIP_MEMORY_SCOPE_AGENT);
            }
        }
    } else {
        // One thread waits on the 1-word flag (relaxed load: NO buffer_inv),
        // then reads the 2 published stats words.
        if (threadIdx.x == 0) {
            while (__hip_atomic_load(line + 1, __ATOMIC_RELAXED,
                                     __HIP_MEMORY_SCOPE_AGENT) == 0) {
                __builtin_amdgcn_s_sleep(2);
            }
            asm volatile("" ::: "memory");  // don't hoist stats loads
            s_mean = __hip_atomic_load(&stats[0], __ATOMIC_RELAXED,
                                       __HIP_MEMORY_SCOPE_AGENT);
            s_inv = __hip_atomic_load(&stats[1], __ATOMIC_RELAXED,
                                      __HIP_MEMORY_SCOPE_AGENT);
        }
    }
    __syncthreads();
    const float mean = s_mean;
    const float inv = s_inv;

    // ---- phase 2: normalize chunk (re-read is L2/L3-served: no cache op
    // ever invalidated it), non-temporal stores keep L3 for the input ----
    v4f* __restrict__ bout = out + base;
#pragma unroll
    for (int i = 0; i < VEC4_PER_THREAD; ++i) {
        const int idx = threadIdx.x + i * THREADS;
        v4f v = bin[idx];
        v4f r;
        r.x = (v.x - mean) * inv;
        r.y = (v.y - mean) * inv;
        r.z = (v.z - mean) * inv;
        r.w = (v.w - mean) * inv;
        __builtin_nontemporal_store(r, &bout[idx]);
    }
}

extern "C" void kernel_launch(void* const* d_in, const int* in_sizes, int n_in,
                              void* d_out, int out_size, void* d_ws, size_t ws_size,
                              hipStream_t stream) {
    const v4f* in = (const v4f*)d_in[0];
    v4f* out = (v4f*)d_out;
    int* ctrl = (int*)d_ws;                             // 8 KiB, zeroed
    float* partials = (float*)((char*)d_ws + 8192);     // 16 KiB, guarded

    hipMemsetAsync(ctrl, 0, N_IMG * CTRL_INTS_PER_IMG * sizeof(int), stream);
    std_fused_nf<<<GRID, THREADS, 0, stream>>>(in, out, ctrl, partials);
}